// Round 1
// baseline (1477.291 us; speedup 1.0000x reference)
//
#include <hip/hip_runtime.h>
#include <math.h>

#define B_ 32
#define N_ 4096
#define D_ 64
#define T_ 12
#define EPS_ 1e-7f

// ---------------------------------------------------------------------------
// Embedding MLP: e = relu(y @ w1 + b1) @ w2 + b2, and v = x.
// lane = position; weights are wave-uniform (scalar path); acc in VGPRs.
// ---------------------------------------------------------------------------
__global__ __launch_bounds__(256, 2) void emb_kernel(
    const int* __restrict__ x, const float* __restrict__ y,
    const float* __restrict__ w1, const float* __restrict__ b1,
    const float* __restrict__ w2, const float* __restrict__ b2,
    float* __restrict__ e_out, int* __restrict__ v_out)
{
    const int i = blockIdx.x * 256 + threadIdx.x;   // position in [0, B*N)
    const float y0 = y[2 * i];
    const float y1 = y[2 * i + 1];

    float h[D_];
#pragma unroll
    for (int jj = 0; jj < D_; ++jj)
        h[jj] = fmaxf(fmaf(y1, w1[D_ + jj], fmaf(y0, w1[jj], b1[jj])), 0.0f);

    float acc[D_];
#pragma unroll
    for (int jj = 0; jj < D_; ++jj) acc[jj] = b2[jj];
#pragma unroll
    for (int k = 0; k < D_; ++k) {
        const float hk = h[k];
#pragma unroll
        for (int jj = 0; jj < D_; ++jj)
            acc[jj] = fmaf(hk, w2[k * D_ + jj], acc[jj]);
    }

    float* eo = e_out + (size_t)i * D_;
#pragma unroll
    for (int jj = 0; jj < D_; jj += 4) {
        float4 vv = make_float4(acc[jj], acc[jj + 1], acc[jj + 2], acc[jj + 3]);
        *(float4*)(eo + jj) = vv;
    }
    v_out[i] = x[i];
}

// ---------------------------------------------------------------------------
// One tree stage. blockIdx.y = 0 -> cn (left/xor outputs), 1 -> bn (right).
// lane = pair position. Input rows 2P,2P+1 are contiguous (128 floats).
// ---------------------------------------------------------------------------
__global__ __launch_bounds__(256, 2) void pair_kernel(
    const float* __restrict__ e_in, const int* __restrict__ v_in,
    float* __restrict__ e_out, int* __restrict__ v_out,
    const float* __restrict__ cn_w1, const float* __restrict__ cn_b1,
    const float* __restrict__ cn_w2, const float* __restrict__ cn_b2,
    const float* __restrict__ bn_w1, const float* __restrict__ bn_b1,
    const float* __restrict__ bn_w2, const float* __restrict__ bn_b2,
    const float* __restrict__ llr_w, const float* __restrict__ llr_b,
    const float* __restrict__ label_emb,
    float* __restrict__ loss_out,   // (B, T, N)
    float* __restrict__ pred1,      // (B, N, T, 2)
    float* __restrict__ pred2,      // copy
    int t, int log2Lh)
{
    const int Q  = blockIdx.x * 256 + threadIdx.x;  // global pair idx [0, B*N/2)
    const int b  = Q >> 11;                          // / (N/2)
    const int P  = Q & (N_ / 2 - 1);
    const int Lh = 1 << log2Lh;
    const int j  = P & (Lh - 1);
    const int outL = 2 * P - j;                      // = blk*L + j
    const int is_bn = blockIdx.y;

    const int r0 = b * N_ + 2 * P;
    const float* __restrict__ inp = e_in + (size_t)r0 * D_;
    const int v0 = v_in[r0];
    const int v1 = v_in[r0 + 1];
    const int vx = (v0 ^ v1) & 1;

    const float* __restrict__ w1p = is_bn ? bn_w1 : cn_w1;
    const float* __restrict__ b1p = is_bn ? bn_b1 : cn_b1;
    const float* __restrict__ w2p = is_bn ? bn_w2 : cn_w2;
    const float* __restrict__ b2p = is_bn ? bn_b2 : cn_b2;

    // ---- layer 1: acc[jj] = b1 + sum_k in[k] * w1[k][jj] ----
    float acc[D_];
#pragma unroll
    for (int jj = 0; jj < D_; ++jj) acc[jj] = b1p[jj];

    for (int k4 = 0; k4 < 32; ++k4) {               // 128 contiguous e inputs
        const float4 ev = *(const float4*)(inp + 4 * k4);
        const float evs[4] = {ev.x, ev.y, ev.z, ev.w};
#pragma unroll
        for (int u = 0; u < 4; ++u) {
            const float ik = evs[u];
            const int k = 4 * k4 + u;
#pragma unroll
            for (int jj = 0; jj < D_; ++jj)
                acc[jj] = fmaf(ik, w1p[k * D_ + jj], acc[jj]);
        }
    }

    if (is_bn) {
        // extra 64 inputs: label_emb[vx][:] (per-lane select of two uniform rows)
        for (int k4 = 0; k4 < 16; ++k4) {
            const float4 l0 = *(const float4*)(label_emb + 4 * k4);
            const float4 l1 = *(const float4*)(label_emb + D_ + 4 * k4);
            const float l0s[4] = {l0.x, l0.y, l0.z, l0.w};
            const float l1s[4] = {l1.x, l1.y, l1.z, l1.w};
#pragma unroll
            for (int u = 0; u < 4; ++u) {
                const float ik = vx ? l1s[u] : l0s[u];
                const int k = 128 + 4 * k4 + u;
#pragma unroll
                for (int jj = 0; jj < D_; ++jj)
                    acc[jj] = fmaf(ik, w1p[k * D_ + jj], acc[jj]);
            }
        }
    }

    // ---- relu + layer 2 ----
#pragma unroll
    for (int jj = 0; jj < D_; ++jj) acc[jj] = fmaxf(acc[jj], 0.0f);

    float acc2[D_];
#pragma unroll
    for (int jj = 0; jj < D_; ++jj) acc2[jj] = b2p[jj];
#pragma unroll
    for (int k = 0; k < D_; ++k) {
        const float hk = acc[k];
#pragma unroll
        for (int jj = 0; jj < D_; ++jj)
            acc2[jj] = fmaf(hk, w2p[k * D_ + jj], acc2[jj]);
    }

    // ---- llr head: logits = acc2 @ llr_w + llr_b, softmax, loss ----
    float z0 = llr_b[0], z1 = llr_b[1];
#pragma unroll
    for (int jj = 0; jj < D_; ++jj) {
        z0 = fmaf(acc2[jj], llr_w[2 * jj], z0);
        z1 = fmaf(acc2[jj], llr_w[2 * jj + 1], z1);
    }
    const float m   = fmaxf(z0, z1);
    const float ex0 = expf(z0 - m);
    const float ex1 = expf(z1 - m);
    const float inv = 1.0f / (ex0 + ex1);
    const float p0  = ex0 * inv;
    const float p1  = ex1 * inv;
    const float c0  = fminf(fmaxf(p0, EPS_), 1.0f - EPS_);
    const float c1  = fminf(fmaxf(p1, EPS_), 1.0f - EPS_);

    const int lab   = is_bn ? (v1 & 1) : vx;
    const float loss = -logf(lab ? c1 : c0);

    const int i_out = is_bn ? (outL + Lh) : outL;
    const int gout  = b * N_ + i_out;

    v_out[gout] = is_bn ? v1 : vx;

    float* eo = e_out + (size_t)gout * D_;
#pragma unroll
    for (int jj = 0; jj < D_; jj += 4) {
        float4 vv = make_float4(acc2[jj], acc2[jj + 1], acc2[jj + 2], acc2[jj + 3]);
        *(float4*)(eo + jj) = vv;
    }

    loss_out[(b * T_ + t) * N_ + i_out] = loss;

    const size_t pb = ((size_t)(b * N_ + i_out) * T_ + t) * 2;
    pred1[pb]     = p0;
    pred1[pb + 1] = p1;
    pred2[pb]     = p0;
    pred2[pb + 1] = p1;
}

// ---------------------------------------------------------------------------
extern "C" void kernel_launch(void* const* d_in, const int* in_sizes, int n_in,
                              void* d_out, int out_size, void* d_ws, size_t ws_size,
                              hipStream_t stream)
{
    const int*   x      = (const int*)  d_in[0];
    const float* y      = (const float*)d_in[1];
    const float* emb_w1 = (const float*)d_in[2];
    const float* emb_b1 = (const float*)d_in[3];
    const float* emb_w2 = (const float*)d_in[4];
    const float* emb_b2 = (const float*)d_in[5];
    const float* cn_w1  = (const float*)d_in[6];
    const float* cn_b1  = (const float*)d_in[7];
    const float* cn_w2  = (const float*)d_in[8];
    const float* cn_b2  = (const float*)d_in[9];
    const float* bn_w1  = (const float*)d_in[10];
    const float* bn_b1  = (const float*)d_in[11];
    const float* bn_w2  = (const float*)d_in[12];
    const float* bn_b2  = (const float*)d_in[13];
    const float* llr_w  = (const float*)d_in[14];
    const float* llr_b  = (const float*)d_in[15];
    const float* label_emb = (const float*)d_in[16];

    float* out      = (float*)d_out;
    float* loss_out = out;                                   // B*T*N
    float* pred1    = out + (size_t)B_ * T_ * N_;            // B*N*T*2
    float* pred2    = pred1 + (size_t)B_ * N_ * T_ * 2;      // copy

    // workspace: e double buffer (2 x 32 MB) + v double buffer
    float* e_a = (float*)d_ws;
    float* e_b = e_a + (size_t)B_ * N_ * D_;
    int*   v_a = (int*)(e_b + (size_t)B_ * N_ * D_);
    int*   v_b = v_a + B_ * N_;

    emb_kernel<<<dim3(B_ * N_ / 256), dim3(256), 0, stream>>>(
        x, y, emb_w1, emb_b1, emb_w2, emb_b2, e_a, v_a);

    float* e_cur = e_a; float* e_nxt = e_b;
    int*   v_cur = v_a; int*   v_nxt = v_b;
    for (int t = 0; t < T_; ++t) {
        pair_kernel<<<dim3(B_ * N_ / 2 / 256, 2), dim3(256), 0, stream>>>(
            e_cur, v_cur, e_nxt, v_nxt,
            cn_w1, cn_b1, cn_w2, cn_b2,
            bn_w1, bn_b1, bn_w2, bn_b2,
            llr_w, llr_b, label_emb,
            loss_out, pred1, pred2, t, 11 - t);
        float* tf = e_cur; e_cur = e_nxt; e_nxt = tf;
        int*   ti = v_cur; v_cur = v_nxt; v_nxt = ti;
    }
}

// Round 2
// 962.152 us; speedup vs baseline: 1.5354x; 1.5354x over previous
//
#include <hip/hip_runtime.h>
#include <math.h>

#define B_ 32
#define N_ 4096
#define D_ 64
#define T_ 12
#define EPS_ 1e-7f
#define PSTR 65   // padded LDS row stride (floats): g-stride 260 -> banks 4g+c, conflict-free

typedef float4 f4;
#define LD4(p) (*(const float4*)(p))

__device__ __forceinline__ float f4c(const float4 v, int q) {
    return q == 0 ? v.x : q == 1 ? v.y : q == 2 ? v.z : v.w;
}

__device__ __forceinline__ void fma8(float (&acc)[8], float a, const float4 w0, const float4 w1) {
    acc[0] = fmaf(a, w0.x, acc[0]); acc[1] = fmaf(a, w0.y, acc[1]);
    acc[2] = fmaf(a, w0.z, acc[2]); acc[3] = fmaf(a, w0.w, acc[3]);
    acc[4] = fmaf(a, w1.x, acc[4]); acc[5] = fmaf(a, w1.y, acc[5]);
    acc[6] = fmaf(a, w1.z, acc[6]); acc[7] = fmaf(a, w1.w, acc[7]);
}

// ---------------------------------------------------------------------------
// Embedding: thread = 4 positions x 8-output slice. K=2 layer1, K=64 layer2.
// ---------------------------------------------------------------------------
__global__ __launch_bounds__(256, 4) void emb_kernel(
    const int* __restrict__ x, const float* __restrict__ y,
    const float* __restrict__ w1, const float* __restrict__ b1,
    const float* __restrict__ w2, const float* __restrict__ b2,
    float* __restrict__ e_out, int* __restrict__ v_out)
{
    __shared__ float h_lds[128 * PSTR];
    const int tid = threadIdx.x;
    const int s   = tid & 7;
    const int g   = tid >> 3;
    const int jj0 = s * 8;
    const int i0  = (blockIdx.x * 32 + g) * 4;   // first position of this group

    // layer 1 (K=2): h = relu(y0*w1[0] + y1*w1[1] + b1), write slice to LDS
    {
        f4 wa0 = LD4(w1 + jj0),      wa1 = LD4(w1 + jj0 + 4);
        f4 wb0 = LD4(w1 + D_ + jj0), wb1 = LD4(w1 + D_ + jj0 + 4);
        f4 bb0 = LD4(b1 + jj0),      bb1 = LD4(b1 + jj0 + 4);
#pragma unroll
        for (int pp = 0; pp < 4; ++pp) {
            const float2 yv = *(const float2*)(y + 2 * (i0 + pp));
            f4 h0, h1;
            h0.x = fmaxf(fmaf(yv.y, wb0.x, fmaf(yv.x, wa0.x, bb0.x)), 0.f);
            h0.y = fmaxf(fmaf(yv.y, wb0.y, fmaf(yv.x, wa0.y, bb0.y)), 0.f);
            h0.z = fmaxf(fmaf(yv.y, wb0.z, fmaf(yv.x, wa0.z, bb0.z)), 0.f);
            h0.w = fmaxf(fmaf(yv.y, wb0.w, fmaf(yv.x, wa0.w, bb0.w)), 0.f);
            h1.x = fmaxf(fmaf(yv.y, wb1.x, fmaf(yv.x, wa1.x, bb1.x)), 0.f);
            h1.y = fmaxf(fmaf(yv.y, wb1.y, fmaf(yv.x, wa1.y, bb1.y)), 0.f);
            h1.z = fmaxf(fmaf(yv.y, wb1.z, fmaf(yv.x, wa1.z, bb1.z)), 0.f);
            h1.w = fmaxf(fmaf(yv.y, wb1.w, fmaf(yv.x, wa1.w, bb1.w)), 0.f);
            float* hp = h_lds + (g * 4 + pp) * PSTR + jj0;
            *(f4*)hp = h0; *(f4*)(hp + 4) = h1;
        }
    }
    __syncthreads();

    // layer 2 (K=64)
    float o[4][8];
    {
        f4 b20 = LD4(b2 + jj0), b21 = LD4(b2 + jj0 + 4);
#pragma unroll
        for (int pp = 0; pp < 4; ++pp) {
            o[pp][0]=b20.x; o[pp][1]=b20.y; o[pp][2]=b20.z; o[pp][3]=b20.w;
            o[pp][4]=b21.x; o[pp][5]=b21.y; o[pp][6]=b21.z; o[pp][7]=b21.w;
        }
    }
#pragma unroll 2
    for (int k4 = 0; k4 < 16; ++k4) {
        const f4 x0 = LD4(h_lds + (g * 4 + 0) * PSTR + 4 * k4);
        const f4 x1 = LD4(h_lds + (g * 4 + 1) * PSTR + 4 * k4);
        const f4 x2 = LD4(h_lds + (g * 4 + 2) * PSTR + 4 * k4);
        const f4 x3 = LD4(h_lds + (g * 4 + 3) * PSTR + 4 * k4);
        const float* wk = w2 + (4 * k4) * D_ + jj0;
#pragma unroll
        for (int q = 0; q < 4; ++q) {
            const f4 wa = LD4(wk + q * D_), wb = LD4(wk + q * D_ + 4);
            fma8(o[0], f4c(x0, q), wa, wb);
            fma8(o[1], f4c(x1, q), wa, wb);
            fma8(o[2], f4c(x2, q), wa, wb);
            fma8(o[3], f4c(x3, q), wa, wb);
        }
    }

#pragma unroll
    for (int pp = 0; pp < 4; ++pp) {
        float* eo = e_out + (size_t)(i0 + pp) * D_ + jj0;
        f4 a = make_float4(o[pp][0], o[pp][1], o[pp][2], o[pp][3]);
        f4 c = make_float4(o[pp][4], o[pp][5], o[pp][6], o[pp][7]);
        *(f4*)eo = a; *(f4*)(eo + 4) = c;
    }
    if (s < 4) v_out[i0 + s] = x[i0 + s];
}

// ---------------------------------------------------------------------------
// One tree stage. blockIdx.y = 0 -> cn, 1 -> bn.
// Thread = 4 pairs x 8-output slice. 8 slice-lanes per group share a wave.
// ---------------------------------------------------------------------------
__global__ __launch_bounds__(256, 4) void pair_kernel(
    const float* __restrict__ e_in, const int* __restrict__ v_in,
    float* __restrict__ e_out, int* __restrict__ v_out,
    const float* __restrict__ cn_w1, const float* __restrict__ cn_b1,
    const float* __restrict__ cn_w2, const float* __restrict__ cn_b2,
    const float* __restrict__ bn_w1, const float* __restrict__ bn_b1,
    const float* __restrict__ bn_w2, const float* __restrict__ bn_b2,
    const float* __restrict__ llr_w, const float* __restrict__ llr_b,
    const float* __restrict__ label_emb,
    float* __restrict__ loss_out,   // (B, T, N)
    float* __restrict__ pred1,      // (B, N, T, 2)
    float* __restrict__ pred2,
    int t, int log2Lh)
{
    __shared__ float h_lds[128 * PSTR];
    const int tid = threadIdx.x;
    const int s   = tid & 7;
    const int g   = tid >> 3;
    const int jj0 = s * 8;
    const int is_bn = blockIdx.y;
    const int p0  = (blockIdx.x * 32 + g) * 4;   // first global pair index
    const int b   = p0 >> 11;
    const int P0  = p0 & 2047;
    const int r0  = 2 * p0;                       // first input row (b*N + 2P)

    const float* __restrict__ w1p = is_bn ? bn_w1 : cn_w1;
    const float* __restrict__ b1p = is_bn ? bn_b1 : cn_b1;
    const float* __restrict__ w2p = is_bn ? bn_w2 : cn_w2;
    const float* __restrict__ b2p = is_bn ? bn_b2 : cn_b2;

    int vx[4], v1a[4];
#pragma unroll
    for (int pp = 0; pp < 4; ++pp) {
        const int2 vv = *(const int2*)(v_in + r0 + 2 * pp);
        v1a[pp] = vv.y & 1;
        vx[pp]  = (vv.x ^ vv.y) & 1;
    }

    // ---- layer 1 ----
    float acc[4][8];
    {
        f4 bb0 = LD4(b1p + jj0), bb1 = LD4(b1p + jj0 + 4);
#pragma unroll
        for (int pp = 0; pp < 4; ++pp) {
            acc[pp][0]=bb0.x; acc[pp][1]=bb0.y; acc[pp][2]=bb0.z; acc[pp][3]=bb0.w;
            acc[pp][4]=bb1.x; acc[pp][5]=bb1.y; acc[pp][6]=bb1.z; acc[pp][7]=bb1.w;
        }
    }
    const float* inp = e_in + (size_t)r0 * D_;   // pair pp input: inp + pp*128, 128 floats

#pragma unroll 2
    for (int k4 = 0; k4 < 32; ++k4) {
        const f4 x0 = LD4(inp + 0 * 128 + 4 * k4);
        const f4 x1 = LD4(inp + 1 * 128 + 4 * k4);
        const f4 x2 = LD4(inp + 2 * 128 + 4 * k4);
        const f4 x3 = LD4(inp + 3 * 128 + 4 * k4);
        const float* wk = w1p + (4 * k4) * D_ + jj0;
#pragma unroll
        for (int q = 0; q < 4; ++q) {
            const f4 wa = LD4(wk + q * D_), wb = LD4(wk + q * D_ + 4);
            fma8(acc[0], f4c(x0, q), wa, wb);
            fma8(acc[1], f4c(x1, q), wa, wb);
            fma8(acc[2], f4c(x2, q), wa, wb);
            fma8(acc[3], f4c(x3, q), wa, wb);
        }
    }

    if (is_bn) {
        const float* le0 = label_emb;
        const float* le1 = label_emb + D_;
#pragma unroll 2
        for (int k4 = 0; k4 < 16; ++k4) {
            const f4 l0 = LD4(le0 + 4 * k4), l1 = LD4(le1 + 4 * k4);
            f4 xs[4];
#pragma unroll
            for (int pp = 0; pp < 4; ++pp) {
                xs[pp].x = vx[pp] ? l1.x : l0.x;
                xs[pp].y = vx[pp] ? l1.y : l0.y;
                xs[pp].z = vx[pp] ? l1.z : l0.z;
                xs[pp].w = vx[pp] ? l1.w : l0.w;
            }
            const float* wk = w1p + (128 + 4 * k4) * D_ + jj0;
#pragma unroll
            for (int q = 0; q < 4; ++q) {
                const f4 wa = LD4(wk + q * D_), wb = LD4(wk + q * D_ + 4);
                fma8(acc[0], f4c(xs[0], q), wa, wb);
                fma8(acc[1], f4c(xs[1], q), wa, wb);
                fma8(acc[2], f4c(xs[2], q), wa, wb);
                fma8(acc[3], f4c(xs[3], q), wa, wb);
            }
        }
    }

    // relu -> LDS
#pragma unroll
    for (int pp = 0; pp < 4; ++pp) {
        float* hp = h_lds + (g * 4 + pp) * PSTR + jj0;
        f4 h0 = make_float4(fmaxf(acc[pp][0],0.f), fmaxf(acc[pp][1],0.f),
                            fmaxf(acc[pp][2],0.f), fmaxf(acc[pp][3],0.f));
        f4 h1 = make_float4(fmaxf(acc[pp][4],0.f), fmaxf(acc[pp][5],0.f),
                            fmaxf(acc[pp][6],0.f), fmaxf(acc[pp][7],0.f));
        *(f4*)hp = h0; *(f4*)(hp + 4) = h1;
    }
    __syncthreads();

    // ---- layer 2 (K=64) ----
    float o[4][8];
    {
        f4 b20 = LD4(b2p + jj0), b21 = LD4(b2p + jj0 + 4);
#pragma unroll
        for (int pp = 0; pp < 4; ++pp) {
            o[pp][0]=b20.x; o[pp][1]=b20.y; o[pp][2]=b20.z; o[pp][3]=b20.w;
            o[pp][4]=b21.x; o[pp][5]=b21.y; o[pp][6]=b21.z; o[pp][7]=b21.w;
        }
    }
#pragma unroll 2
    for (int k4 = 0; k4 < 16; ++k4) {
        const f4 x0 = LD4(h_lds + (g * 4 + 0) * PSTR + 4 * k4);
        const f4 x1 = LD4(h_lds + (g * 4 + 1) * PSTR + 4 * k4);
        const f4 x2 = LD4(h_lds + (g * 4 + 2) * PSTR + 4 * k4);
        const f4 x3 = LD4(h_lds + (g * 4 + 3) * PSTR + 4 * k4);
        const float* wk = w2p + (4 * k4) * D_ + jj0;
#pragma unroll
        for (int q = 0; q < 4; ++q) {
            const f4 wa = LD4(wk + q * D_), wb = LD4(wk + q * D_ + 4);
            fma8(o[0], f4c(x0, q), wa, wb);
            fma8(o[1], f4c(x1, q), wa, wb);
            fma8(o[2], f4c(x2, q), wa, wb);
            fma8(o[3], f4c(x3, q), wa, wb);
        }
    }

    // ---- llr head: per-slice partials, reduce over the 8 slice lanes ----
    const f4 lw0 = LD4(llr_w + 16 * s),      lw1 = LD4(llr_w + 16 * s + 4);
    const f4 lw2 = LD4(llr_w + 16 * s + 8),  lw3 = LD4(llr_w + 16 * s + 12);
    float z0[4], z1[4];
#pragma unroll
    for (int pp = 0; pp < 4; ++pp) {
        float a0 = o[pp][0]*lw0.x + o[pp][1]*lw0.z + o[pp][2]*lw1.x + o[pp][3]*lw1.z
                 + o[pp][4]*lw2.x + o[pp][5]*lw2.z + o[pp][6]*lw3.x + o[pp][7]*lw3.z;
        float a1 = o[pp][0]*lw0.y + o[pp][1]*lw0.w + o[pp][2]*lw1.y + o[pp][3]*lw1.w
                 + o[pp][4]*lw2.y + o[pp][5]*lw2.w + o[pp][6]*lw3.y + o[pp][7]*lw3.w;
        z0[pp] = a0; z1[pp] = a1;
    }
#pragma unroll
    for (int pp = 0; pp < 4; ++pp) {
        z0[pp] += __shfl_xor(z0[pp], 1); z1[pp] += __shfl_xor(z1[pp], 1);
        z0[pp] += __shfl_xor(z0[pp], 2); z1[pp] += __shfl_xor(z1[pp], 2);
        z0[pp] += __shfl_xor(z0[pp], 4); z1[pp] += __shfl_xor(z1[pp], 4);
    }

    // ---- outputs ----
    const int Lh = 1 << log2Lh;
    int i_outA[4], goutA[4];
#pragma unroll
    for (int pp = 0; pp < 4; ++pp) {
        const int P  = P0 + pp;
        const int j  = P & (Lh - 1);
        const int io = 2 * P - j + (is_bn ? Lh : 0);
        i_outA[pp] = io;
        goutA[pp]  = b * N_ + io;
    }
#pragma unroll
    for (int pp = 0; pp < 4; ++pp) {
        float* eo = e_out + (size_t)goutA[pp] * D_ + jj0;
        f4 a = make_float4(o[pp][0], o[pp][1], o[pp][2], o[pp][3]);
        f4 c = make_float4(o[pp][4], o[pp][5], o[pp][6], o[pp][7]);
        *(f4*)eo = a; *(f4*)(eo + 4) = c;
    }
    if (s < 4) {
        const int pp = s;
        const float zz0 = z0[pp] + llr_b[0], zz1 = z1[pp] + llr_b[1];
        const float m   = fmaxf(zz0, zz1);
        const float e0  = expf(zz0 - m), e1 = expf(zz1 - m);
        const float inv = 1.0f / (e0 + e1);
        const float p0s = e0 * inv, p1s = e1 * inv;
        const float c0  = fminf(fmaxf(p0s, EPS_), 1.0f - EPS_);
        const float c1  = fminf(fmaxf(p1s, EPS_), 1.0f - EPS_);
        const int   lab = is_bn ? v1a[pp] : vx[pp];
        const float loss = -logf(lab ? c1 : c0);
        const int io = i_outA[pp], go = goutA[pp];
        v_out[go] = is_bn ? v1a[pp] : vx[pp];
        loss_out[(b * T_ + t) * N_ + io] = loss;
        const size_t pb = ((size_t)go * T_ + t) * 2;
        *(float2*)(pred1 + pb) = make_float2(p0s, p1s);
        *(float2*)(pred2 + pb) = make_float2(p0s, p1s);
    }
}

// ---------------------------------------------------------------------------
extern "C" void kernel_launch(void* const* d_in, const int* in_sizes, int n_in,
                              void* d_out, int out_size, void* d_ws, size_t ws_size,
                              hipStream_t stream)
{
    const int*   x      = (const int*)  d_in[0];
    const float* y      = (const float*)d_in[1];
    const float* emb_w1 = (const float*)d_in[2];
    const float* emb_b1 = (const float*)d_in[3];
    const float* emb_w2 = (const float*)d_in[4];
    const float* emb_b2 = (const float*)d_in[5];
    const float* cn_w1  = (const float*)d_in[6];
    const float* cn_b1  = (const float*)d_in[7];
    const float* cn_w2  = (const float*)d_in[8];
    const float* cn_b2  = (const float*)d_in[9];
    const float* bn_w1  = (const float*)d_in[10];
    const float* bn_b1  = (const float*)d_in[11];
    const float* bn_w2  = (const float*)d_in[12];
    const float* bn_b2  = (const float*)d_in[13];
    const float* llr_w  = (const float*)d_in[14];
    const float* llr_b  = (const float*)d_in[15];
    const float* label_emb = (const float*)d_in[16];

    float* out      = (float*)d_out;
    float* loss_out = out;                                   // B*T*N
    float* pred1    = out + (size_t)B_ * T_ * N_;            // B*N*T*2
    float* pred2    = pred1 + (size_t)B_ * N_ * T_ * 2;

    float* e_a = (float*)d_ws;
    float* e_b = e_a + (size_t)B_ * N_ * D_;
    int*   v_a = (int*)(e_b + (size_t)B_ * N_ * D_);
    int*   v_b = v_a + B_ * N_;

    emb_kernel<<<dim3(B_ * N_ / 4 / 32), dim3(256), 0, stream>>>(
        x, y, emb_w1, emb_b1, emb_w2, emb_b2, e_a, v_a);

    float* e_cur = e_a; float* e_nxt = e_b;
    int*   v_cur = v_a; int*   v_nxt = v_b;
    for (int t = 0; t < T_; ++t) {
        pair_kernel<<<dim3(B_ * N_ / 2 / 4 / 32, 2), dim3(256), 0, stream>>>(
            e_cur, v_cur, e_nxt, v_nxt,
            cn_w1, cn_b1, cn_w2, cn_b2,
            bn_w1, bn_b1, bn_w2, bn_b2,
            llr_w, llr_b, label_emb,
            loss_out, pred1, pred2, t, 11 - t);
        float* tf = e_cur; e_cur = e_nxt; e_nxt = tf;
        int*   ti = v_cur; v_cur = v_nxt; v_nxt = ti;
    }
}

// Round 4
// 401.395 us; speedup vs baseline: 3.6804x; 2.3970x over previous
//
#include <hip/hip_runtime.h>
#include <math.h>

#define B_ 32
#define N_ 4096
#define D_ 64
#define T_ 12
#define EPS_ 1e-7f
#define PSTR 65

typedef float4 f4;
#define LD4(p) (*(const float4*)(p))

typedef __attribute__((ext_vector_type(8))) short short8;
typedef __attribute__((ext_vector_type(4))) float f32x4;
#define MFMA(a, b, c) __builtin_amdgcn_mfma_f32_16x16x32_bf16(a, b, c, 0, 0, 0)

__device__ __forceinline__ float f4c(const float4 v, int q) {
    return q == 0 ? v.x : q == 1 ? v.y : q == 2 ? v.z : v.w;
}
__device__ __forceinline__ void fma8(float (&acc)[8], float a, const float4 w0, const float4 w1) {
    acc[0] = fmaf(a, w0.x, acc[0]); acc[1] = fmaf(a, w0.y, acc[1]);
    acc[2] = fmaf(a, w0.z, acc[2]); acc[3] = fmaf(a, w0.w, acc[3]);
    acc[4] = fmaf(a, w1.x, acc[4]); acc[5] = fmaf(a, w1.y, acc[5]);
    acc[6] = fmaf(a, w1.z, acc[6]); acc[7] = fmaf(a, w1.w, acc[7]);
}

// split fp32 -> bf16 hi (truncate) + bf16 lo (truncated remainder): a ~= hi + lo, rel err ~2^-16
__device__ __forceinline__ void splitbf(float a, short& h, short& l) {
    unsigned x = __float_as_uint(a);
    h = (short)(x >> 16);
    float r = a - __uint_as_float(x & 0xffff0000u);
    l = (short)(__float_as_uint(r) >> 16);
}
// packed u32: low16 = hi-bf16, high16 = lo-bf16
__device__ __forceinline__ unsigned packsplit(float a) {
    unsigned x = __float_as_uint(a);
    unsigned hib = x & 0xffff0000u;
    float r = a - __uint_as_float(hib);
    return (x >> 16) | (__float_as_uint(r) & 0xffff0000u);
}
__device__ __forceinline__ float unpackf(unsigned p) {
    return __uint_as_float(p << 16) + __uint_as_float(p & 0xffff0000u);
}

// ---------------------------------------------------------------------------
// Prep: pack weights into MFMA B-fragment order (hi/lo planes) + bn contrib.
// B-frag layout for 16x16x32: lane n=l&15, k=kt*32+(l>>4)*8+e.
// ---------------------------------------------------------------------------
__global__ void prep_kernel(
    const float* __restrict__ cn_w1, const float* __restrict__ cn_w2,
    const float* __restrict__ bn_w1, const float* __restrict__ bn_w2,
    const float* __restrict__ bn_b1, const float* __restrict__ label_emb,
    short* __restrict__ p_cn1h, short* __restrict__ p_cn1l,
    short* __restrict__ p_bn1h, short* __restrict__ p_bn1l,
    short* __restrict__ p_cn2h, short* __restrict__ p_cn2l,
    short* __restrict__ p_bn2h, short* __restrict__ p_bn2l,
    float* __restrict__ contrib)
{
    const int tid = threadIdx.x;
    for (int idx = tid; idx < 8192; idx += 256) {   // w1 packs (K=128)
        const int e = idx & 7, l = (idx >> 3) & 63, fb = idx >> 9;
        const int kt = fb >> 2, nt = fb & 3;
        const int k = kt * 32 + (l >> 4) * 8 + e;
        const int n = nt * 16 + (l & 15);
        short h, lo;
        splitbf(cn_w1[k * 64 + n], h, lo); p_cn1h[idx] = h; p_cn1l[idx] = lo;
        splitbf(bn_w1[k * 64 + n], h, lo); p_bn1h[idx] = h; p_bn1l[idx] = lo;
    }
    for (int idx = tid; idx < 4096; idx += 256) {   // w2 packs (K=64)
        const int e = idx & 7, l = (idx >> 3) & 63, fb = idx >> 9;
        const int kt = fb >> 2, nt = fb & 3;
        const int k = kt * 32 + (l >> 4) * 8 + e;
        const int n = nt * 16 + (l & 15);
        short h, lo;
        splitbf(cn_w2[k * 64 + n], h, lo); p_cn2h[idx] = h; p_cn2l[idx] = lo;
        splitbf(bn_w2[k * 64 + n], h, lo); p_bn2h[idx] = h; p_bn2l[idx] = lo;
    }
    if (tid < 128) {                                 // contrib[c][n] = b1[n] + le[c]@bn_w1[128:]
        const int c = tid >> 6, n = tid & 63;
        float s = bn_b1[n];
        for (int kk = 0; kk < 64; ++kk)
            s = fmaf(label_emb[c * 64 + kk], bn_w1[(128 + kk) * 64 + n], s);
        contrib[c * 64 + n] = s;
    }
}

// ---------------------------------------------------------------------------
// Embedding (fp32 vector; small). Writes e as bf16 hi/lo planes.
// ---------------------------------------------------------------------------
__global__ __launch_bounds__(256, 4) void emb_kernel(
    const int* __restrict__ x, const float* __restrict__ y,
    const float* __restrict__ w1, const float* __restrict__ b1,
    const float* __restrict__ w2, const float* __restrict__ b2,
    short* __restrict__ e_hi, short* __restrict__ e_lo, int* __restrict__ v_out)
{
    __shared__ float h_lds[128 * PSTR];
    const int tid = threadIdx.x;
    const int s   = tid & 7;
    const int g   = tid >> 3;
    const int jj0 = s * 8;
    const int i0  = (blockIdx.x * 32 + g) * 4;

    {
        f4 wa0 = LD4(w1 + jj0),      wa1 = LD4(w1 + jj0 + 4);
        f4 wb0 = LD4(w1 + D_ + jj0), wb1 = LD4(w1 + D_ + jj0 + 4);
        f4 bb0 = LD4(b1 + jj0),      bb1 = LD4(b1 + jj0 + 4);
#pragma unroll
        for (int pp = 0; pp < 4; ++pp) {
            const float2 yv = *(const float2*)(y + 2 * (i0 + pp));
            f4 h0, h1;
            h0.x = fmaxf(fmaf(yv.y, wb0.x, fmaf(yv.x, wa0.x, bb0.x)), 0.f);
            h0.y = fmaxf(fmaf(yv.y, wb0.y, fmaf(yv.x, wa0.y, bb0.y)), 0.f);
            h0.z = fmaxf(fmaf(yv.y, wb0.z, fmaf(yv.x, wa0.z, bb0.z)), 0.f);
            h0.w = fmaxf(fmaf(yv.y, wb0.w, fmaf(yv.x, wa0.w, bb0.w)), 0.f);
            h1.x = fmaxf(fmaf(yv.y, wb1.x, fmaf(yv.x, wa1.x, bb1.x)), 0.f);
            h1.y = fmaxf(fmaf(yv.y, wb1.y, fmaf(yv.x, wa1.y, bb1.y)), 0.f);
            h1.z = fmaxf(fmaf(yv.y, wb1.z, fmaf(yv.x, wa1.z, bb1.z)), 0.f);
            h1.w = fmaxf(fmaf(yv.y, wb1.w, fmaf(yv.x, wa1.w, bb1.w)), 0.f);
            float* hp = h_lds + (g * 4 + pp) * PSTR + jj0;
            *(f4*)hp = h0; *(f4*)(hp + 4) = h1;
        }
    }
    __syncthreads();

    float o[4][8];
    {
        f4 b20 = LD4(b2 + jj0), b21 = LD4(b2 + jj0 + 4);
#pragma unroll
        for (int pp = 0; pp < 4; ++pp) {
            o[pp][0]=b20.x; o[pp][1]=b20.y; o[pp][2]=b20.z; o[pp][3]=b20.w;
            o[pp][4]=b21.x; o[pp][5]=b21.y; o[pp][6]=b21.z; o[pp][7]=b21.w;
        }
    }
#pragma unroll 2
    for (int k4 = 0; k4 < 16; ++k4) {
        const f4 x0 = LD4(h_lds + (g * 4 + 0) * PSTR + 4 * k4);
        const f4 x1 = LD4(h_lds + (g * 4 + 1) * PSTR + 4 * k4);
        const f4 x2 = LD4(h_lds + (g * 4 + 2) * PSTR + 4 * k4);
        const f4 x3 = LD4(h_lds + (g * 4 + 3) * PSTR + 4 * k4);
        const float* wk = w2 + (4 * k4) * D_ + jj0;
#pragma unroll
        for (int q = 0; q < 4; ++q) {
            const f4 wa = LD4(wk + q * D_), wb = LD4(wk + q * D_ + 4);
            fma8(o[0], f4c(x0, q), wa, wb);
            fma8(o[1], f4c(x1, q), wa, wb);
            fma8(o[2], f4c(x2, q), wa, wb);
            fma8(o[3], f4c(x3, q), wa, wb);
        }
    }

#pragma unroll
    for (int pp = 0; pp < 4; ++pp) {
        const size_t base = (size_t)(i0 + pp) * D_ + jj0;
        union { short s[8]; uint4 v; } uh, ul;
#pragma unroll
        for (int q = 0; q < 8; ++q) splitbf(o[pp][q], uh.s[q], ul.s[q]);
        *(uint4*)(e_hi + base) = uh.v;
        *(uint4*)(e_lo + base) = ul.v;
    }
    if (s < 4) v_out[i0 + s] = x[i0 + s];
}

// ---------------------------------------------------------------------------
// One tree stage, both nets, MFMA bf16 hi/lo split (3-term).
// Wave = 16 pairs x 64 outs. Block = 4 waves, wave-private LDS tiles.
// ---------------------------------------------------------------------------
__global__ __launch_bounds__(256, 3) void pair_mfma(
    const short* __restrict__ e_hi, const short* __restrict__ e_lo,
    const int* __restrict__ v_in,
    short* __restrict__ eo_hi, short* __restrict__ eo_lo, int* __restrict__ v_out,
    const short* __restrict__ p_cn1h, const short* __restrict__ p_cn1l,
    const short* __restrict__ p_bn1h, const short* __restrict__ p_bn1l,
    const short* __restrict__ p_cn2h, const short* __restrict__ p_cn2l,
    const short* __restrict__ p_bn2h, const short* __restrict__ p_bn2l,
    const float* __restrict__ cn_b1, const float* __restrict__ cn_b2,
    const float* __restrict__ bn_b2, const float* __restrict__ contrib,
    const float* __restrict__ llr_w, const float* __restrict__ llr_b,
    float* __restrict__ loss_out, float* __restrict__ pred1, float* __restrict__ pred2,
    int t, int log2Lh)
{
    __shared__ unsigned int lds[4][2][16][68];
    const int tid  = threadIdx.x;
    const int wid  = tid >> 6, lane = tid & 63;
    const int rowm = lane & 15, kg = lane >> 4;
    const int P0   = (blockIdx.x * 4 + wid) * 16;
    const int b    = P0 >> 11;

    // ---- A fragments (shared by cn and bn, K=128) ----
    short8 Ah[4], Al[4];
#pragma unroll
    for (int kt = 0; kt < 4; ++kt) {
        const size_t pos = (size_t)(2 * (P0 + rowm) + (kt >> 1));
        const int off = (kt & 1) * 32 + kg * 8;
        Ah[kt] = *(const short8*)(e_hi + pos * D_ + off);
        Al[kt] = *(const short8*)(e_lo + pos * D_ + off);
    }

    // vx per accumulator row (D rows m = kg*4+r)
    int vxm[4];
#pragma unroll
    for (int r = 0; r < 4; ++r) {
        const int2 vv = *(const int2*)(v_in + 2 * (P0 + kg * 4 + r));
        vxm[r] = (vv.x ^ vv.y) & 1;
    }

    // ---- layer 1 accumulators ----
    f32x4 aC[4], aB[4];
#pragma unroll
    for (int nt = 0; nt < 4; ++nt) {
        const float bc = cn_b1[nt * 16 + rowm];
        aC[nt] = (f32x4){bc, bc, bc, bc};
        f32x4 ab;
#pragma unroll
        for (int r = 0; r < 4; ++r) ab[r] = contrib[vxm[r] * 64 + nt * 16 + rowm];
        aB[nt] = ab;
    }

#pragma unroll
    for (int kt = 0; kt < 4; ++kt) {
#pragma unroll
        for (int nt = 0; nt < 4; ++nt) {
            const int fo = ((kt * 4 + nt) * 64 + lane) * 8;
            const short8 bh = *(const short8*)(p_cn1h + fo);
            const short8 bl = *(const short8*)(p_cn1l + fo);
            aC[nt] = MFMA(Ah[kt], bh, aC[nt]);
            aC[nt] = MFMA(Al[kt], bh, aC[nt]);
            aC[nt] = MFMA(Ah[kt], bl, aC[nt]);
            const short8 ch = *(const short8*)(p_bn1h + fo);
            const short8 cl = *(const short8*)(p_bn1l + fo);
            aB[nt] = MFMA(Ah[kt], ch, aB[nt]);
            aB[nt] = MFMA(Al[kt], ch, aB[nt]);
            aB[nt] = MFMA(Ah[kt], cl, aB[nt]);
        }
    }

    // ---- relu + split -> LDS (wave-private; D-layout write, A-layout read) ----
#pragma unroll
    for (int nt = 0; nt < 4; ++nt)
#pragma unroll
        for (int r = 0; r < 4; ++r) {
            lds[wid][0][kg * 4 + r][nt * 16 + rowm] = packsplit(fmaxf(aC[nt][r], 0.f));
            lds[wid][1][kg * 4 + r][nt * 16 + rowm] = packsplit(fmaxf(aB[nt][r], 0.f));
        }
    __builtin_amdgcn_wave_barrier();

#pragma unroll
    for (int net = 0; net < 2; ++net) {
        const short* __restrict__ w2h = net ? p_bn2h : p_cn2h;
        const short* __restrict__ w2l = net ? p_bn2l : p_cn2l;
        const float* __restrict__ b2  = net ? bn_b2 : cn_b2;

        f32x4 o[4];
#pragma unroll
        for (int nt = 0; nt < 4; ++nt) {
            const float bb = b2[nt * 16 + rowm];
            o[nt] = (f32x4){bb, bb, bb, bb};
        }

#pragma unroll
        for (int kt = 0; kt < 2; ++kt) {
            unsigned xa[8];
#pragma unroll
            for (int e2 = 0; e2 < 8; ++e2)
                xa[e2] = lds[wid][net][rowm][kt * 32 + kg * 8 + e2];
            union { short8 s; unsigned u[4]; } ah, al;
#pragma unroll
            for (int j = 0; j < 4; ++j) {
                const unsigned x0 = xa[2 * j], x1 = xa[2 * j + 1];
                ah.u[j] = (x0 & 0xffffu) | (x1 << 16);
                al.u[j] = (x0 >> 16) | (x1 & 0xffff0000u);
            }
#pragma unroll
            for (int nt = 0; nt < 4; ++nt) {
                const int fo = ((kt * 4 + nt) * 64 + lane) * 8;
                const short8 bh = *(const short8*)(w2h + fo);
                const short8 bl = *(const short8*)(w2l + fo);
                o[nt] = MFMA(ah.s, bh, o[nt]);
                o[nt] = MFMA(al.s, bh, o[nt]);
                o[nt] = MFMA(ah.s, bl, o[nt]);
            }
        }

        __builtin_amdgcn_wave_barrier();
        // e_new -> LDS (reuse this net's h tile; same-wave only)
#pragma unroll
        for (int nt = 0; nt < 4; ++nt)
#pragma unroll
            for (int r = 0; r < 4; ++r)
                lds[wid][net][kg * 4 + r][nt * 16 + rowm] = packsplit(o[nt][r]);
        __builtin_amdgcn_wave_barrier();

        // ---- epilogue: quad of lanes per pair ----
        const int mp = lane >> 2, cs = lane & 3;
        const int gp = P0 + mp;
        const int P  = gp & 2047;
        const int Lh = 1 << log2Lh;
        const int jj = P & (Lh - 1);
        const int io = 2 * P - jj + (net ? Lh : 0);
        const int gout = b * N_ + io;

        unsigned xe[16];
#pragma unroll
        for (int i = 0; i < 16; ++i) xe[i] = lds[wid][net][mp][cs * 16 + i];

        float z0 = 0.f, z1 = 0.f;
#pragma unroll
        for (int i = 0; i < 16; i += 2) {
            const float4 w = LD4(llr_w + 2 * (cs * 16 + i));
            const float ev0 = unpackf(xe[i]);
            const float ev1 = unpackf(xe[i + 1]);
            z0 = fmaf(ev0, w.x, z0); z1 = fmaf(ev0, w.y, z1);
            z0 = fmaf(ev1, w.z, z0); z1 = fmaf(ev1, w.w, z1);
        }
        z0 += __shfl_xor(z0, 1); z1 += __shfl_xor(z1, 1);
        z0 += __shfl_xor(z0, 2); z1 += __shfl_xor(z1, 2);

        unsigned hiw[8], low[8];
#pragma unroll
        for (int i2 = 0; i2 < 8; ++i2) {
            const unsigned x0 = xe[2 * i2], x1 = xe[2 * i2 + 1];
            hiw[i2] = (x0 & 0xffffu) | (x1 << 16);
            low[i2] = (x0 >> 16) | (x1 & 0xffff0000u);
        }
        {
            const size_t eb = (size_t)gout * D_ + cs * 16;
            *(uint4*)(eo_hi + eb)     = make_uint4(hiw[0], hiw[1], hiw[2], hiw[3]);
            *(uint4*)(eo_hi + eb + 8) = make_uint4(hiw[4], hiw[5], hiw[6], hiw[7]);
            *(uint4*)(eo_lo + eb)     = make_uint4(low[0], low[1], low[2], low[3]);
            *(uint4*)(eo_lo + eb + 8) = make_uint4(low[4], low[5], low[6], low[7]);
        }

        if (cs == 0) {
            const int2 vv = *(const int2*)(v_in + 2 * gp);
            const int vx = (vv.x ^ vv.y) & 1;
            const float zz0 = z0 + llr_b[0], zz1 = z1 + llr_b[1];
            const float m   = fmaxf(zz0, zz1);
            const float ex0 = expf(zz0 - m), ex1 = expf(zz1 - m);
            const float inv = 1.0f / (ex0 + ex1);
            const float p0s = ex0 * inv, p1s = ex1 * inv;
            const float c0  = fminf(fmaxf(p0s, EPS_), 1.0f - EPS_);
            const float c1  = fminf(fmaxf(p1s, EPS_), 1.0f - EPS_);
            const int   lab = net ? (vv.y & 1) : vx;
            const float loss = -logf(lab ? c1 : c0);
            v_out[gout] = net ? vv.y : vx;
            loss_out[(b * T_ + t) * N_ + io] = loss;
            const size_t pb = ((size_t)gout * T_ + t) * 2;
            *(float2*)(pred1 + pb) = make_float2(p0s, p1s);
            *(float2*)(pred2 + pb) = make_float2(p0s, p1s);
        }
    }
}

// ---------------------------------------------------------------------------
extern "C" void kernel_launch(void* const* d_in, const int* in_sizes, int n_in,
                              void* d_out, int out_size, void* d_ws, size_t ws_size,
                              hipStream_t stream)
{
    const int*   x      = (const int*)  d_in[0];
    const float* y      = (const float*)d_in[1];
    const float* emb_w1 = (const float*)d_in[2];
    const float* emb_b1 = (const float*)d_in[3];
    const float* emb_w2 = (const float*)d_in[4];
    const float* emb_b2 = (const float*)d_in[5];
    const float* cn_w1  = (const float*)d_in[6];
    const float* cn_b1  = (const float*)d_in[7];
    const float* cn_w2  = (const float*)d_in[8];
    const float* cn_b2  = (const float*)d_in[9];
    const float* bn_w1  = (const float*)d_in[10];
    const float* bn_b1  = (const float*)d_in[11];
    const float* bn_w2  = (const float*)d_in[12];
    const float* bn_b2  = (const float*)d_in[13];
    const float* llr_w  = (const float*)d_in[14];
    const float* llr_b  = (const float*)d_in[15];
    const float* label_emb = (const float*)d_in[16];

    float* out      = (float*)d_out;
    float* loss_out = out;
    float* pred1    = out + (size_t)B_ * T_ * N_;
    float* pred2    = pred1 + (size_t)B_ * N_ * T_ * 2;

    const size_t EPLANE = (size_t)B_ * N_ * D_;
    short* eh_a = (short*)d_ws;
    short* el_a = eh_a + EPLANE;
    short* eh_b = el_a + EPLANE;
    short* el_b = eh_b + EPLANE;
    int*   v_a  = (int*)(el_b + EPLANE);
    int*   v_b  = v_a + B_ * N_;
    short* p_cn1h = (short*)(v_b + B_ * N_);
    short* p_cn1l = p_cn1h + 8192;
    short* p_bn1h = p_cn1l + 8192;
    short* p_bn1l = p_bn1h + 8192;
    short* p_cn2h = p_bn1l + 8192;
    short* p_cn2l = p_cn2h + 4096;
    short* p_bn2h = p_cn2l + 4096;
    short* p_bn2l = p_bn2h + 4096;
    float* contrib = (float*)(p_bn2l + 4096);

    prep_kernel<<<1, 256, 0, stream>>>(
        cn_w1, cn_w2, bn_w1, bn_w2, bn_b1, label_emb,
        p_cn1h, p_cn1l, p_bn1h, p_bn1l, p_cn2h, p_cn2l, p_bn2h, p_bn2l, contrib);

    emb_kernel<<<dim3(B_ * N_ / 128), dim3(256), 0, stream>>>(
        x, y, emb_w1, emb_b1, emb_w2, emb_b2, eh_a, el_a, v_a);

    short* ehc = eh_a; short* elc = el_a; short* ehn = eh_b; short* eln = el_b;
    int* vc = v_a; int* vn = v_b;
    for (int t = 0; t < T_; ++t) {
        pair_mfma<<<dim3(B_ * N_ / 2 / 64), dim3(256), 0, stream>>>(
            ehc, elc, vc, ehn, eln, vn,
            p_cn1h, p_cn1l, p_bn1h, p_bn1l, p_cn2h, p_cn2l, p_bn2h, p_bn2l,
            cn_b1, cn_b2, bn_b2, contrib, llr_w, llr_b,
            loss_out, pred1, pred2, t, 11 - t);
        short* t1 = ehc; ehc = ehn; ehn = t1;
        short* t2 = elc; elc = eln; eln = t2;
        int* t3 = vc; vc = vn; vn = t3;
    }
}

// Round 6
// 365.080 us; speedup vs baseline: 4.0465x; 1.0995x over previous
//
#include <hip/hip_runtime.h>
#include <math.h>

#define B_ 32
#define N_ 4096
#define D_ 64
#define T_ 12
#define EPS_ 1e-7f
#define PSTR 65

typedef float4 f4;
#define LD4(p) (*(const float4*)(p))

typedef __attribute__((ext_vector_type(8))) short short8;
typedef __attribute__((ext_vector_type(4))) float f32x4;
#define MFMA(a, b, c) __builtin_amdgcn_mfma_f32_16x16x32_bf16(a, b, c, 0, 0, 0)

__device__ __forceinline__ float f4c(const float4 v, int q) {
    return q == 0 ? v.x : q == 1 ? v.y : q == 2 ? v.z : v.w;
}
__device__ __forceinline__ void fma8(float (&acc)[8], float a, const float4 w0, const float4 w1) {
    acc[0] = fmaf(a, w0.x, acc[0]); acc[1] = fmaf(a, w0.y, acc[1]);
    acc[2] = fmaf(a, w0.z, acc[2]); acc[3] = fmaf(a, w0.w, acc[3]);
    acc[4] = fmaf(a, w1.x, acc[4]); acc[5] = fmaf(a, w1.y, acc[5]);
    acc[6] = fmaf(a, w1.z, acc[6]); acc[7] = fmaf(a, w1.w, acc[7]);
}

// split fp32 -> bf16 hi (truncate) + bf16 lo (truncated remainder): a ~= hi + lo, rel err ~2^-16
__device__ __forceinline__ void splitbf(float a, short& h, short& l) {
    unsigned x = __float_as_uint(a);
    h = (short)(x >> 16);
    float r = a - __uint_as_float(x & 0xffff0000u);
    l = (short)(__float_as_uint(r) >> 16);
}
// packed u32: low16 = hi-bf16, high16 = lo-bf16
__device__ __forceinline__ unsigned packsplit(float a) {
    unsigned x = __float_as_uint(a);
    unsigned hib = x & 0xffff0000u;
    float r = a - __uint_as_float(hib);
    return (x >> 16) | (__float_as_uint(r) & 0xffff0000u);
}
__device__ __forceinline__ float unpackf(unsigned p) {
    return __uint_as_float(p << 16) + __uint_as_float(p & 0xffff0000u);
}

// ---------------------------------------------------------------------------
// Prep: pack weights into MFMA B-fragment order (hi/lo planes) + bn contrib.
// B-frag layout for 16x16x32: lane n=l&15, k=kt*32+(l>>4)*8+e.
// ---------------------------------------------------------------------------
__global__ void prep_kernel(
    const float* __restrict__ cn_w1, const float* __restrict__ cn_w2,
    const float* __restrict__ bn_w1, const float* __restrict__ bn_w2,
    const float* __restrict__ bn_b1, const float* __restrict__ label_emb,
    short* __restrict__ p_cn1h, short* __restrict__ p_cn1l,
    short* __restrict__ p_bn1h, short* __restrict__ p_bn1l,
    short* __restrict__ p_cn2h, short* __restrict__ p_cn2l,
    short* __restrict__ p_bn2h, short* __restrict__ p_bn2l,
    float* __restrict__ contrib)
{
    const int tid = threadIdx.x;
    for (int idx = tid; idx < 8192; idx += 256) {   // w1 packs (K=128)
        const int e = idx & 7, l = (idx >> 3) & 63, fb = idx >> 9;
        const int kt = fb >> 2, nt = fb & 3;
        const int k = kt * 32 + (l >> 4) * 8 + e;
        const int n = nt * 16 + (l & 15);
        short h, lo;
        splitbf(cn_w1[k * 64 + n], h, lo); p_cn1h[idx] = h; p_cn1l[idx] = lo;
        splitbf(bn_w1[k * 64 + n], h, lo); p_bn1h[idx] = h; p_bn1l[idx] = lo;
    }
    for (int idx = tid; idx < 4096; idx += 256) {   // w2 packs (K=64)
        const int e = idx & 7, l = (idx >> 3) & 63, fb = idx >> 9;
        const int kt = fb >> 2, nt = fb & 3;
        const int k = kt * 32 + (l >> 4) * 8 + e;
        const int n = nt * 16 + (l & 15);
        short h, lo;
        splitbf(cn_w2[k * 64 + n], h, lo); p_cn2h[idx] = h; p_cn2l[idx] = lo;
        splitbf(bn_w2[k * 64 + n], h, lo); p_bn2h[idx] = h; p_bn2l[idx] = lo;
    }
    if (tid < 128) {                                 // contrib[c][n] = b1[n] + le[c]@bn_w1[128:]
        const int c = tid >> 6, n = tid & 63;
        float s = bn_b1[n];
        for (int kk = 0; kk < 64; ++kk)
            s = fmaf(label_emb[c * 64 + kk], bn_w1[(128 + kk) * 64 + n], s);
        contrib[c * 64 + n] = s;
    }
}

// ---------------------------------------------------------------------------
// Embedding (fp32 vector; small). Writes e as bf16 hi/lo planes.
// ---------------------------------------------------------------------------
__global__ __launch_bounds__(256, 4) void emb_kernel(
    const int* __restrict__ x, const float* __restrict__ y,
    const float* __restrict__ w1, const float* __restrict__ b1,
    const float* __restrict__ w2, const float* __restrict__ b2,
    short* __restrict__ e_hi, short* __restrict__ e_lo, int* __restrict__ v_out)
{
    __shared__ float h_lds[128 * PSTR];
    const int tid = threadIdx.x;
    const int s   = tid & 7;
    const int g   = tid >> 3;
    const int jj0 = s * 8;
    const int i0  = (blockIdx.x * 32 + g) * 4;

    {
        f4 wa0 = LD4(w1 + jj0),      wa1 = LD4(w1 + jj0 + 4);
        f4 wb0 = LD4(w1 + D_ + jj0), wb1 = LD4(w1 + D_ + jj0 + 4);
        f4 bb0 = LD4(b1 + jj0),      bb1 = LD4(b1 + jj0 + 4);
#pragma unroll
        for (int pp = 0; pp < 4; ++pp) {
            const float2 yv = *(const float2*)(y + 2 * (i0 + pp));
            f4 h0, h1;
            h0.x = fmaxf(fmaf(yv.y, wb0.x, fmaf(yv.x, wa0.x, bb0.x)), 0.f);
            h0.y = fmaxf(fmaf(yv.y, wb0.y, fmaf(yv.x, wa0.y, bb0.y)), 0.f);
            h0.z = fmaxf(fmaf(yv.y, wb0.z, fmaf(yv.x, wa0.z, bb0.z)), 0.f);
            h0.w = fmaxf(fmaf(yv.y, wb0.w, fmaf(yv.x, wa0.w, bb0.w)), 0.f);
            h1.x = fmaxf(fmaf(yv.y, wb1.x, fmaf(yv.x, wa1.x, bb1.x)), 0.f);
            h1.y = fmaxf(fmaf(yv.y, wb1.y, fmaf(yv.x, wa1.y, bb1.y)), 0.f);
            h1.z = fmaxf(fmaf(yv.y, wb1.z, fmaf(yv.x, wa1.z, bb1.z)), 0.f);
            h1.w = fmaxf(fmaf(yv.y, wb1.w, fmaf(yv.x, wa1.w, bb1.w)), 0.f);
            float* hp = h_lds + (g * 4 + pp) * PSTR + jj0;
            *(f4*)hp = h0; *(f4*)(hp + 4) = h1;
        }
    }
    __syncthreads();

    float o[4][8];
    {
        f4 b20 = LD4(b2 + jj0), b21 = LD4(b2 + jj0 + 4);
#pragma unroll
        for (int pp = 0; pp < 4; ++pp) {
            o[pp][0]=b20.x; o[pp][1]=b20.y; o[pp][2]=b20.z; o[pp][3]=b20.w;
            o[pp][4]=b21.x; o[pp][5]=b21.y; o[pp][6]=b21.z; o[pp][7]=b21.w;
        }
    }
#pragma unroll 2
    for (int k4 = 0; k4 < 16; ++k4) {
        const f4 x0 = LD4(h_lds + (g * 4 + 0) * PSTR + 4 * k4);
        const f4 x1 = LD4(h_lds + (g * 4 + 1) * PSTR + 4 * k4);
        const f4 x2 = LD4(h_lds + (g * 4 + 2) * PSTR + 4 * k4);
        const f4 x3 = LD4(h_lds + (g * 4 + 3) * PSTR + 4 * k4);
        const float* wk = w2 + (4 * k4) * D_ + jj0;
#pragma unroll
        for (int q = 0; q < 4; ++q) {
            const f4 wa = LD4(wk + q * D_), wb = LD4(wk + q * D_ + 4);
            fma8(o[0], f4c(x0, q), wa, wb);
            fma8(o[1], f4c(x1, q), wa, wb);
            fma8(o[2], f4c(x2, q), wa, wb);
            fma8(o[3], f4c(x3, q), wa, wb);
        }
    }

#pragma unroll
    for (int pp = 0; pp < 4; ++pp) {
        const size_t base = (size_t)(i0 + pp) * D_ + jj0;
        union { short s[8]; uint4 v; } uh, ul;
#pragma unroll
        for (int q = 0; q < 8; ++q) splitbf(o[pp][q], uh.s[q], ul.s[q]);
        *(uint4*)(e_hi + base) = uh.v;
        *(uint4*)(e_lo + base) = ul.v;
    }
    if (s < 4) v_out[i0 + s] = x[i0 + s];
}

// ---------------------------------------------------------------------------
// One tree stage, both nets, MFMA bf16 hi/lo split (3-term).
// Wave = 32 pairs (2 M-subtiles) x 64 outs: each B-fragment load feeds 2
// subtiles -> halves L2 weight refetch. Block = 4 waves, wave-private LDS.
// ---------------------------------------------------------------------------
__global__ __launch_bounds__(256, 2) void pair_mfma(
    const short* __restrict__ e_hi, const short* __restrict__ e_lo,
    const int* __restrict__ v_in,
    short* __restrict__ eo_hi, short* __restrict__ eo_lo, int* __restrict__ v_out,
    const short* __restrict__ p_cn1h, const short* __restrict__ p_cn1l,
    const short* __restrict__ p_bn1h, const short* __restrict__ p_bn1l,
    const short* __restrict__ p_cn2h, const short* __restrict__ p_cn2l,
    const short* __restrict__ p_bn2h, const short* __restrict__ p_bn2l,
    const float* __restrict__ cn_b1, const float* __restrict__ cn_b2,
    const float* __restrict__ bn_b2, const float* __restrict__ contrib,
    const float* __restrict__ llr_w, const float* __restrict__ llr_b,
    float* __restrict__ loss_out, float* __restrict__ pred1, float* __restrict__ pred2,
    int t, int log2Lh)
{
    __shared__ unsigned int lds[4][2][32][68];   // 69632 B -> 2 blocks/CU
    const int tid  = threadIdx.x;
    const int wid  = tid >> 6, lane = tid & 63;
    const int rowm = lane & 15, kg = lane >> 4;
    const int P0   = (blockIdx.x * 4 + wid) * 32;
    const int b    = P0 >> 11;

    // vx per accumulator row: sub s, row m = kg*4+r -> pair P0 + s*16 + m
    int vxm[2][4];
#pragma unroll
    for (int s = 0; s < 2; ++s)
#pragma unroll
        for (int r = 0; r < 4; ++r) {
            const int2 vv = *(const int2*)(v_in + 2 * (P0 + s * 16 + kg * 4 + r));
            vxm[s][r] = (vv.x ^ vv.y) & 1;
        }

    // ---- layer 1 accumulators ----
    f32x4 aC[2][4], aB[2][4];
#pragma unroll
    for (int nt = 0; nt < 4; ++nt) {
        const float bc = cn_b1[nt * 16 + rowm];
#pragma unroll
        for (int s = 0; s < 2; ++s) {
            aC[s][nt] = (f32x4){bc, bc, bc, bc};
            f32x4 ab;
#pragma unroll
            for (int r = 0; r < 4; ++r) ab[r] = contrib[vxm[s][r] * 64 + nt * 16 + rowm];
            aB[s][nt] = ab;
        }
    }

    // ---- layer 1: K=128, A transient per kt, B frags shared by both subtiles
#pragma unroll
    for (int kt = 0; kt < 4; ++kt) {
        short8 Ah[2], Al[2];
#pragma unroll
        for (int s = 0; s < 2; ++s) {
            const size_t pos = (size_t)(2 * (P0 + s * 16 + rowm) + (kt >> 1));
            const int off = (kt & 1) * 32 + kg * 8;
            Ah[s] = *(const short8*)(e_hi + pos * D_ + off);
            Al[s] = *(const short8*)(e_lo + pos * D_ + off);
        }
#pragma unroll
        for (int nt = 0; nt < 4; ++nt) {
            const int fo = ((kt * 4 + nt) * 64 + lane) * 8;
            const short8 bh = *(const short8*)(p_cn1h + fo);
            const short8 bl = *(const short8*)(p_cn1l + fo);
            const short8 ch = *(const short8*)(p_bn1h + fo);
            const short8 cl = *(const short8*)(p_bn1l + fo);
#pragma unroll
            for (int s = 0; s < 2; ++s) {
                aC[s][nt] = MFMA(Ah[s], bh, aC[s][nt]);
                aC[s][nt] = MFMA(Al[s], bh, aC[s][nt]);
                aC[s][nt] = MFMA(Ah[s], bl, aC[s][nt]);
                aB[s][nt] = MFMA(Ah[s], ch, aB[s][nt]);
                aB[s][nt] = MFMA(Al[s], ch, aB[s][nt]);
                aB[s][nt] = MFMA(Ah[s], cl, aB[s][nt]);
            }
        }
    }

    // ---- relu + split -> LDS (wave-private; D-layout write, A-layout read)
#pragma unroll
    for (int s = 0; s < 2; ++s)
#pragma unroll
        for (int nt = 0; nt < 4; ++nt)
#pragma unroll
            for (int r = 0; r < 4; ++r) {
                lds[wid][0][s * 16 + kg * 4 + r][nt * 16 + rowm] = packsplit(fmaxf(aC[s][nt][r], 0.f));
                lds[wid][1][s * 16 + kg * 4 + r][nt * 16 + rowm] = packsplit(fmaxf(aB[s][nt][r], 0.f));
            }
    __builtin_amdgcn_wave_barrier();

#pragma unroll
    for (int net = 0; net < 2; ++net) {
        const short* __restrict__ w2h = net ? p_bn2h : p_cn2h;
        const short* __restrict__ w2l = net ? p_bn2l : p_cn2l;
        const float* __restrict__ b2  = net ? bn_b2 : cn_b2;

        f32x4 o[2][4];
#pragma unroll
        for (int nt = 0; nt < 4; ++nt) {
            const float bb = b2[nt * 16 + rowm];
#pragma unroll
            for (int s = 0; s < 2; ++s) o[s][nt] = (f32x4){bb, bb, bb, bb};
        }

#pragma unroll
        for (int kt = 0; kt < 2; ++kt) {
            short8 ah[2], al[2];
#pragma unroll
            for (int s = 0; s < 2; ++s) {
                unsigned xa[8];
#pragma unroll
                for (int e2 = 0; e2 < 8; ++e2)
                    xa[e2] = lds[wid][net][s * 16 + rowm][kt * 32 + kg * 8 + e2];
                union { short8 sv; unsigned u[4]; } th, tl;
#pragma unroll
                for (int j = 0; j < 4; ++j) {
                    const unsigned x0 = xa[2 * j], x1 = xa[2 * j + 1];
                    th.u[j] = (x0 & 0xffffu) | (x1 << 16);
                    tl.u[j] = (x0 >> 16) | (x1 & 0xffff0000u);
                }
                ah[s] = th.sv; al[s] = tl.sv;
            }
#pragma unroll
            for (int nt = 0; nt < 4; ++nt) {
                const int fo = ((kt * 4 + nt) * 64 + lane) * 8;
                const short8 bh = *(const short8*)(w2h + fo);
                const short8 bl = *(const short8*)(w2l + fo);
#pragma unroll
                for (int s = 0; s < 2; ++s) {
                    o[s][nt] = MFMA(ah[s], bh, o[s][nt]);
                    o[s][nt] = MFMA(al[s], bh, o[s][nt]);
                    o[s][nt] = MFMA(ah[s], bl, o[s][nt]);
                }
            }
        }

        __builtin_amdgcn_wave_barrier();
        // e_new -> LDS (reuse this net's h tile; same-wave only)
#pragma unroll
        for (int s = 0; s < 2; ++s)
#pragma unroll
            for (int nt = 0; nt < 4; ++nt)
#pragma unroll
                for (int r = 0; r < 4; ++r)
                    lds[wid][net][s * 16 + kg * 4 + r][nt * 16 + rowm] = packsplit(o[s][nt][r]);
        __builtin_amdgcn_wave_barrier();

        // ---- epilogue: quad of lanes per pair, per subtile ----
        const int mp = lane >> 2, cs = lane & 3;
        const int Lh = 1 << log2Lh;
#pragma unroll
        for (int s = 0; s < 2; ++s) {
            const int gp = P0 + s * 16 + mp;
            const int P  = gp & 2047;
            const int jj = P & (Lh - 1);
            const int io = 2 * P - jj + (net ? Lh : 0);
            const int gout = b * N_ + io;

            unsigned xe[16];
#pragma unroll
            for (int i = 0; i < 16; ++i) xe[i] = lds[wid][net][s * 16 + mp][cs * 16 + i];

            float z0 = 0.f, z1 = 0.f;
#pragma unroll
            for (int i = 0; i < 16; i += 2) {
                const float4 w = LD4(llr_w + 2 * (cs * 16 + i));
                const float ev0 = unpackf(xe[i]);
                const float ev1 = unpackf(xe[i + 1]);
                z0 = fmaf(ev0, w.x, z0); z1 = fmaf(ev0, w.y, z1);
                z0 = fmaf(ev1, w.z, z0); z1 = fmaf(ev1, w.w, z1);
            }
            z0 += __shfl_xor(z0, 1); z1 += __shfl_xor(z1, 1);
            z0 += __shfl_xor(z0, 2); z1 += __shfl_xor(z1, 2);

            unsigned hiw[8], low[8];
#pragma unroll
            for (int i2 = 0; i2 < 8; ++i2) {
                const unsigned x0 = xe[2 * i2], x1 = xe[2 * i2 + 1];
                hiw[i2] = (x0 & 0xffffu) | (x1 << 16);
                low[i2] = (x0 >> 16) | (x1 & 0xffff0000u);
            }
            {
                const size_t eb = (size_t)gout * D_ + cs * 16;
                *(uint4*)(eo_hi + eb)     = make_uint4(hiw[0], hiw[1], hiw[2], hiw[3]);
                *(uint4*)(eo_hi + eb + 8) = make_uint4(hiw[4], hiw[5], hiw[6], hiw[7]);
                *(uint4*)(eo_lo + eb)     = make_uint4(low[0], low[1], low[2], low[3]);
                *(uint4*)(eo_lo + eb + 8) = make_uint4(low[4], low[5], low[6], low[7]);
            }

            if (cs == 0) {
                const int2 vv = *(const int2*)(v_in + 2 * gp);
                const int vx = (vv.x ^ vv.y) & 1;
                const float zz0 = z0 + llr_b[0], zz1 = z1 + llr_b[1];
                const float m   = fmaxf(zz0, zz1);
                const float ex0 = expf(zz0 - m), ex1 = expf(zz1 - m);
                const float inv = 1.0f / (ex0 + ex1);
                const float p0s = ex0 * inv, p1s = ex1 * inv;
                const float c0  = fminf(fmaxf(p0s, EPS_), 1.0f - EPS_);
                const float c1  = fminf(fmaxf(p1s, EPS_), 1.0f - EPS_);
                const int   lab = net ? (vv.y & 1) : vx;
                const float loss = -logf(lab ? c1 : c0);
                v_out[gout] = net ? vv.y : vx;
                loss_out[(b * T_ + t) * N_ + io] = loss;
                const size_t pb = ((size_t)gout * T_ + t) * 2;
                *(float2*)(pred1 + pb) = make_float2(p0s, p1s);
                *(float2*)(pred2 + pb) = make_float2(p0s, p1s);
            }
        }
    }
}

// ---------------------------------------------------------------------------
extern "C" void kernel_launch(void* const* d_in, const int* in_sizes, int n_in,
                              void* d_out, int out_size, void* d_ws, size_t ws_size,
                              hipStream_t stream)
{
    const int*   x      = (const int*)  d_in[0];
    const float* y      = (const float*)d_in[1];
    const float* emb_w1 = (const float*)d_in[2];
    const float* emb_b1 = (const float*)d_in[3];
    const float* emb_w2 = (const float*)d_in[4];
    const float* emb_b2 = (const float*)d_in[5];
    const float* cn_w1  = (const float*)d_in[6];
    const float* cn_b1  = (const float*)d_in[7];
    const float* cn_w2  = (const float*)d_in[8];
    const float* cn_b2  = (const float*)d_in[9];
    const float* bn_w1  = (const float*)d_in[10];
    const float* bn_b1  = (const float*)d_in[11];
    const float* bn_w2  = (const float*)d_in[12];
    const float* bn_b2  = (const float*)d_in[13];
    const float* llr_w  = (const float*)d_in[14];
    const float* llr_b  = (const float*)d_in[15];
    const float* label_emb = (const float*)d_in[16];

    float* out      = (float*)d_out;
    float* loss_out = out;
    float* pred1    = out + (size_t)B_ * T_ * N_;
    float* pred2    = pred1 + (size_t)B_ * N_ * T_ * 2;

    const size_t EPLANE = (size_t)B_ * N_ * D_;
    short* eh_a = (short*)d_ws;
    short* el_a = eh_a + EPLANE;
    short* eh_b = el_a + EPLANE;
    short* el_b = eh_b + EPLANE;
    int*   v_a  = (int*)(el_b + EPLANE);
    int*   v_b  = v_a + B_ * N_;
    short* p_cn1h = (short*)(v_b + B_ * N_);
    short* p_cn1l = p_cn1h + 8192;
    short* p_bn1h = p_cn1l + 8192;
    short* p_bn1l = p_bn1h + 8192;
    short* p_cn2h = p_bn1l + 8192;
    short* p_cn2l = p_cn2h + 4096;
    short* p_bn2h = p_cn2l + 4096;
    short* p_bn2l = p_bn2h + 4096;
    float* contrib = (float*)(p_bn2l + 4096);

    prep_kernel<<<1, 256, 0, stream>>>(
        cn_w1, cn_w2, bn_w1, bn_w2, bn_b1, label_emb,
        p_cn1h, p_cn1l, p_bn1h, p_bn1l, p_cn2h, p_cn2l, p_bn2h, p_bn2l, contrib);

    emb_kernel<<<dim3(B_ * N_ / 128), dim3(256), 0, stream>>>(
        x, y, emb_w1, emb_b1, emb_w2, emb_b2, eh_a, el_a, v_a);

    short* ehc = eh_a; short* elc = el_a; short* ehn = eh_b; short* eln = el_b;
    int* vc = v_a; int* vn = v_b;
    for (int t = 0; t < T_; ++t) {
        pair_mfma<<<dim3(B_ * N_ / 2 / 128), dim3(256), 0, stream>>>(
            ehc, elc, vc, ehn, eln, vn,
            p_cn1h, p_cn1l, p_bn1h, p_bn1l, p_cn2h, p_cn2l, p_bn2h, p_bn2l,
            cn_b1, cn_b2, bn_b2, contrib, llr_w, llr_b,
            loss_out, pred1, pred2, t, 11 - t);
        short* t1 = ehc; ehc = ehn; ehn = t1;
        short* t2 = elc; elc = eln; eln = t2;
        int* t3 = vc; vc = vn; vn = t3;
    }
}